// Round 1
// baseline (165.904 us; speedup 1.0000x reference)
//
#include <hip/hip_runtime.h>

#define D_MODEL 1024
#define TOKENS_PER_BLOCK 16

// out[tok][d] = t^2 * A[d] + t * B[d] + C[d]
//   A[d] = W[d,0]+W[d,3]+W[d,6]+W[d,9]
//   B[d] = W[d,1]+W[d,2]+2W[d,4]+2W[d,8]+2W[d,10]
//   C[d] = W[d,2]+2W[d,4]-W[d,5]+W[d,8]+W[d,10]+bias[d]
// Thread i handles d = 4i..4i+3 (256 threads cover D_MODEL=1024 exactly).
__global__ __launch_bounds__(256) void n2_embed_kernel(
    const int* __restrict__ toks,
    const float* __restrict__ W,
    const float* __restrict__ bias,
    float* __restrict__ out,
    int n_tokens)
{
    const int d0 = threadIdx.x * 4;

    float A[4], B[4], C[4];
#pragma unroll
    for (int j = 0; j < 4; ++j) {
        const float* w = W + (size_t)(d0 + j) * 12;
        float w0 = w[0], w1 = w[1], w2 = w[2], w3 = w[3];
        float w4 = w[4], w5 = w[5], w6 = w[6];
        float w8 = w[8], w9 = w[9], w10 = w[10];
        A[j] = (w0 + w3) + (w6 + w9);
        B[j] = w1 + w2 + 2.0f * w4 + 2.0f * w8 + 2.0f * w10;
        C[j] = w2 + 2.0f * w4 - w5 + w8 + w10 + bias[d0 + j];
    }

    const int tok_begin = blockIdx.x * TOKENS_PER_BLOCK;
    const int tok_end = min(tok_begin + TOKENS_PER_BLOCK, n_tokens);

    for (int tok = tok_begin; tok < tok_end; ++tok) {
        float t = (float)toks[tok];
        float t2 = t * t;
        float4 o;
        o.x = fmaf(t2, A[0], fmaf(t, B[0], C[0]));
        o.y = fmaf(t2, A[1], fmaf(t, B[1], C[1]));
        o.z = fmaf(t2, A[2], fmaf(t, B[2], C[2]));
        o.w = fmaf(t2, A[3], fmaf(t, B[3], C[3]));
        *(float4*)(out + (size_t)tok * D_MODEL + d0) = o;
    }
}

extern "C" void kernel_launch(void* const* d_in, const int* in_sizes, int n_in,
                              void* d_out, int out_size, void* d_ws, size_t ws_size,
                              hipStream_t stream) {
    const int* toks = (const int*)d_in[0];       // N_tokens [4,8192] int32
    const float* W = (const float*)d_in[1];      // [1024,12]
    const float* bias = (const float*)d_in[2];   // [1024]
    float* out = (float*)d_out;                  // [4,8192,1024] fp32

    int n_tokens = out_size / D_MODEL;           // 32768
    int blocks = (n_tokens + TOKENS_PER_BLOCK - 1) / TOKENS_PER_BLOCK;  // 2048

    n2_embed_kernel<<<blocks, 256, 0, stream>>>(toks, W, bias, out, n_tokens);
}

// Round 3
// 142.412 us; speedup vs baseline: 1.1650x; 1.1650x over previous
//
#include <hip/hip_runtime.h>

#define D_MODEL 1024
#define TOKENS_PER_BLOCK 8

typedef float vfloat4 __attribute__((ext_vector_type(4)));

// out[tok][d] = t^2 * A[d] + t * B[d] + C[d]   (t = float(N_tokens[tok]))
//   A[d] = W[d,0]+W[d,3]+W[d,6]+W[d,9]
//   B[d] = W[d,1]+W[d,2]+2W[d,4]+2W[d,8]+2W[d,10]
//   C[d] = W[d,2]+2W[d,4]-W[d,5]+W[d,8]+W[d,10]+bias[d]
// Thread i handles d = 4i..4i+3 (256 threads cover D_MODEL=1024 exactly).
// Pure streaming-write kernel: nontemporal (nt) float4 stores to avoid L2
// write-allocate churn (output 134 MB >> 32 MiB aggregate L2).
__global__ __launch_bounds__(256) void n2_embed_kernel(
    const int* __restrict__ toks,
    const float* __restrict__ W,
    const float* __restrict__ bias,
    float* __restrict__ out,
    int n_tokens)
{
    const int d0 = threadIdx.x * 4;

    float A[4], B[4], C[4];
#pragma unroll
    for (int j = 0; j < 4; ++j) {
        const float* w = W + (size_t)(d0 + j) * 12;
        float w0 = w[0], w1 = w[1], w2 = w[2], w3 = w[3];
        float w4 = w[4], w5 = w[5], w6 = w[6];
        float w8 = w[8], w9 = w[9], w10 = w[10];
        A[j] = (w0 + w3) + (w6 + w9);
        B[j] = w1 + w2 + 2.0f * w4 + 2.0f * w8 + 2.0f * w10;
        C[j] = w2 + 2.0f * w4 - w5 + w8 + w10 + bias[d0 + j];
    }

    const int tok_begin = blockIdx.x * TOKENS_PER_BLOCK;

    // Prefetch all token values up front (independent loads).
    float tvals[TOKENS_PER_BLOCK];
#pragma unroll
    for (int i = 0; i < TOKENS_PER_BLOCK; ++i) {
        int tok = tok_begin + i;
        tvals[i] = (tok < n_tokens) ? (float)toks[tok] : 0.0f;
    }

#pragma unroll
    for (int i = 0; i < TOKENS_PER_BLOCK; ++i) {
        int tok = tok_begin + i;
        if (tok >= n_tokens) break;
        float t = tvals[i];
        float t2 = t * t;
        vfloat4 o;
        o.x = fmaf(t2, A[0], fmaf(t, B[0], C[0]));
        o.y = fmaf(t2, A[1], fmaf(t, B[1], C[1]));
        o.z = fmaf(t2, A[2], fmaf(t, B[2], C[2]));
        o.w = fmaf(t2, A[3], fmaf(t, B[3], C[3]));
        __builtin_nontemporal_store(o, (vfloat4*)(out + (size_t)tok * D_MODEL + d0));
    }
}

extern "C" void kernel_launch(void* const* d_in, const int* in_sizes, int n_in,
                              void* d_out, int out_size, void* d_ws, size_t ws_size,
                              hipStream_t stream) {
    const int* toks = (const int*)d_in[0];       // N_tokens [4,8192] (int32 view)
    const float* W = (const float*)d_in[1];      // [1024,12]
    const float* bias = (const float*)d_in[2];   // [1024]
    float* out = (float*)d_out;                  // [4,8192,1024] fp32

    int n_tokens = out_size / D_MODEL;           // 32768
    int blocks = (n_tokens + TOKENS_PER_BLOCK - 1) / TOKENS_PER_BLOCK;  // 4096

    n2_embed_kernel<<<blocks, 256, 0, stream>>>(toks, W, bias, out, n_tokens);
}